// Round 12
// baseline (1216.287 us; speedup 1.0000x reference)
//
#include <hip/hip_runtime.h>
#include <hip/hip_bf16.h>
#include <hip/hip_fp16.h>
#include <math.h>

#define BATCH 8192
#define IN_F 5000
#define KP1 5024          // enc1 K padded to mult of 32
#define NN0 512
#define NN1 512
#define NN2 256
#define NTREAT 20
#define OUTF (2*IN_F)     // 10000
#define NP3 10240         // dec3 N padded to mult of 256

typedef _Float16 f16;
typedef _Float16 f16x8 __attribute__((ext_vector_type(8)));
typedef float f32x4 __attribute__((ext_vector_type(4)));
typedef __attribute__((address_space(3))) void as3_void;
typedef const __attribute__((address_space(1))) void cas1_void;

__device__ __forceinline__ int fswz(int row) { return (row >> 1) & 3; }

__device__ __forceinline__ float softplusf(float x) {
    return fmaxf(x, 0.f) + log1pf(expf(-fabsf(x)));
}

// ---------------- prep: gating ----------------
__global__ void zero64_kernel(int* __restrict__ p) {
    if (threadIdx.x < 64) p[threadIdx.x] = 0;
}
__global__ void count_kernel(const int* __restrict__ treat, int* __restrict__ cnt) {
    int b = blockIdx.x * blockDim.x + threadIdx.x;
    if (b >= BATCH) return;
    int t0 = treat[2*b], t1 = treat[2*b+1];
    if (t0 >= 1 && t0 <= NTREAT) atomicAdd(&cnt[t0], 1);
    if (t1 >= 1 && t1 <= NTREAT && t1 != t0) atomicAdd(&cnt[t1], 1);
}
__global__ void pair_kernel(const int* __restrict__ treat, const int* __restrict__ cnt,
                            int* __restrict__ epair) {
    int b = blockIdx.x * blockDim.x + threadIdx.x;
    if (b >= BATCH) return;
    int t0 = treat[2*b], t1 = treat[2*b+1];
    int e0 = (t0 >= 1 && t0 <= NTREAT && cnt[t0] > 1) ? (t0 - 1) : -1;
    int e1 = (t1 >= 1 && t1 <= NTREAT && t1 != t0 && cnt[t1] > 1) ? (t1 - 1) : -1;
    epair[2*b] = e0;
    epair[2*b+1] = e1;
}
__global__ void scatter_kernel(const int* __restrict__ epair, int* __restrict__ pos,
                               int* __restrict__ rows) {
    int b = blockIdx.x * blockDim.x + threadIdx.x;
    if (b >= BATCH) return;
    #pragma unroll
    for (int p = 0; p < 2; ++p) {
        int t = epair[2*b + p];
        if (t >= 0) {
            int x = atomicAdd(&pos[t], 1);
            rows[t * BATCH + x] = b * 2 + p;
        }
    }
}

// ---------------- weight convert: W[K][N] f32 -> Whi/Wlo [Np][Kp] f16 ----------------
// transposed, zero-padded, pre-swizzled: k-group q of row n at slot (q&3) ^ fswz(n)
__global__ __launch_bounds__(256) void convw_kernel(
    const float* __restrict__ W, f16* __restrict__ Whi, f16* __restrict__ Wlo,
    int K, int N, int Kp) {
    __shared__ float t[64][65];
    const int k0 = blockIdx.x * 64;
    const int n0 = blockIdx.y * 64;
    const int tid = threadIdx.x;
    #pragma unroll
    for (int i = 0; i < 16; ++i) {
        int idx = tid + i*256;
        int r = idx >> 6, c = idx & 63;
        float v = 0.f;
        if (k0 + r < K && n0 + c < N) v = W[(size_t)(k0+r)*N + n0 + c];
        t[r][c] = v;
    }
    __syncthreads();
    const int n = tid >> 2;
    const int q0 = (tid & 3) * 2;
    const int f = fswz(n0 + n);
    #pragma unroll
    for (int h = 0; h < 2; ++h) {
        int q = q0 + h;
        if (k0 + q*8 >= Kp) continue;
        f16x8 hv, lv;
        #pragma unroll
        for (int j = 0; j < 8; ++j) {
            float x = t[q*8 + j][n];
            f16 hi = (f16)x;
            hv[j] = hi;
            lv[j] = (f16)(x - (float)hi);
        }
        size_t base = (size_t)(n0 + n) * Kp + (size_t)(k0 + (((q & 3) ^ f) << 3) + (q >> 2) * 32);
        *(f16x8*)&Whi[base] = hv;
        *(f16x8*)&Wlo[base] = lv;
    }
}

// ---------------- grouped expert GEMM ----------------
// Writes only rows assigned to an expert; unassigned rows are never read
// downstream (latconv gates on epair), so no zero-init memset is needed.
__global__ __launch_bounds__(256) void expert_gemm(
    const float* __restrict__ emb, const float* __restrict__ T_W,
    const float* __restrict__ T_b, const int* __restrict__ pos,
    const int* __restrict__ rows, float* __restrict__ latA, float* __restrict__ latB) {
    const int t = blockIdx.x;
    const int n = pos[t];
    const int base = blockIdx.y * 16;
    if (base >= n) return;
    const int nr = min(16, n - base);
    __shared__ float se[16][256];
    __shared__ int ridx[16];
    const int tid = threadIdx.x;
    if (tid < 16) ridx[tid] = (tid < nr) ? rows[t * BATCH + base + tid] : 0;
    __syncthreads();
    #pragma unroll
    for (int s = 0; s < 16; ++s)
        se[s][tid] = (s < nr) ? emb[(size_t)(ridx[s] >> 1) * NN2 + tid] : 0.f;
    __syncthreads();
    float acc[16];
    const float bcol = T_b[t * NN2 + tid];
    #pragma unroll
    for (int s = 0; s < 16; ++s) acc[s] = bcol;
    const float* W = T_W + (size_t)t * NN2 * NN2 + tid;
    for (int d0 = 0; d0 < NN2; d0 += 4) {
        float w0 = W[(size_t)(d0+0) * NN2];
        float w1 = W[(size_t)(d0+1) * NN2];
        float w2 = W[(size_t)(d0+2) * NN2];
        float w3 = W[(size_t)(d0+3) * NN2];
        #pragma unroll
        for (int s = 0; s < 16; ++s) {
            float4 e = *(const float4*)&se[s][d0];
            acc[s] = fmaf(e.x, w0, fmaf(e.y, w1, fmaf(e.z, w2, fmaf(e.w, w3, acc[s]))));
        }
    }
    for (int s = 0; s < nr; ++s) {
        int rp = ridx[s];
        float* dst = (rp & 1) ? latB : latA;
        dst[(size_t)(rp >> 1) * NN2 + tid] = fmaxf(acc[s], 0.f);
    }
}

// latent = gated(latA) + gated(latB) -> hi/lo f16, pre-swizzled layout
// Gate on epair: slot p contributes only if epair[2m+p] >= 0 (expert assigned).
// Unassigned slots hold stale workspace data and must read as zero.
__global__ __launch_bounds__(256) void latconv_kernel(
    const float* __restrict__ latA, const float* __restrict__ latB,
    const int* __restrict__ epair,
    f16* __restrict__ lhi, f16* __restrict__ llo) {
    const int idx = blockIdx.x * 256 + threadIdx.x;
    const int m = idx >> 8, k = idx & 255;
    const float a = (epair[2*m]     >= 0) ? latA[idx] : 0.f;
    const float b = (epair[2*m + 1] >= 0) ? latB[idx] : 0.f;
    float v = a + b;
    f16 hi = (f16)v;
    size_t o = (size_t)m * NN2 + (size_t)(k ^ (fswz(m) << 3));
    lhi[o] = hi;
    llo[o] = (f16)(v - (float)hi);
}

// ---------------- gemm8: tiled MFMA GEMM, dbuf LDS, hi/lo f16 3-term ----------------
// (R1/R2-proven deep path; plain grid. Used for enc1/enc2/dec1/dec2.)
//   BM=256 BN= 64: 512 thr, waves 4m x 2n, per-wave  64x32, LDS  80 KB (2 blk/CU)
// DEEP path (non-XCVT): counted-vmcnt pipeline, prefetch depth 2.
// XCVT path (enc1): old __syncthreads structure (preconv tested R10: neutral,
// dropped — the 8x input re-read is L3-served and conversion overlaps MFMA).
// MODE 0: f32 relu. MODE 1: hi/lo f16 pre-swizzled relu (pitch NpOut).
template<int MODE, bool XCVT, int BN, int BM = 256>
__global__ __launch_bounds__((BM == 128) ? 256 : 512, 2) void gemm8(
    const f16* __restrict__ Xhi, const f16* __restrict__ Xlo,
    const float* __restrict__ X32, int ldx,
    const f16* __restrict__ Whi, const f16* __restrict__ Wlo,
    const float* __restrict__ bias,
    float* __restrict__ C32, f16* __restrict__ Chi, f16* __restrict__ Clo,
    int Kp, int K_real, int N_real, int NpOut, int halfN) {
    constexpr int NTH = (BM == 128) ? 256 : 512;
    constexpr int NWAVE = NTH / 64;
    constexpr int WN_WAVES = (BN == 256) ? 4 : 2;
    constexpr int WM_WAVES = NWAVE / WN_WAVES;
    constexpr int WMT = BM / WM_WAVES;
    constexpr int WNT = BN / WN_WAVES;
    constexpr int MF = WMT / 16;
    constexpr int NF = WNT / 16;
    constexpr int XSZ = BM * 32;
    constexpr int WSZ = BN * 32;
    constexpr int GLL = (BN == 64) ? 5 : 8;
    __shared__ f16 lds[2][2*XSZ + 2*WSZ];

    const int tid = threadIdx.x;
    const int wid = tid >> 6;
    const int lane = tid & 63;
    const int lr = lane & 15;
    const int ls = lane >> 4;
    const int m0 = blockIdx.y * BM;
    const int n0 = blockIdx.x * BN;
    const int wm = (wid / WN_WAVES) * WMT;
    const int wn = (wid % WN_WAVES) * WNT;
    const int koff = ((ls ^ ((lr >> 1) & 3)) << 3);
    const int nk = Kp / 32;

    f32x4 acc[MF][NF] = {};

    auto stage = [&](int bi, int kt) {
        f16* Xh = lds[bi];
        f16* Xl = Xh + XSZ;
        f16* Wh = Xl + XSZ;
        f16* Wl = Wh + WSZ;
        const int kk = kt * 32 + (lane & 3) * 8;
        const int rlo = lane >> 2;
        if constexpr (BN == 128) {
            #pragma unroll
            for (int c = 0; c < 2; ++c) {
                const int rb = wid * 32 + c * 16;
                const size_t g = (size_t)(n0 + rb + rlo) * Kp + kk;
                __builtin_amdgcn_global_load_lds((cas1_void*)(Whi + g), (as3_void*)(Wh + rb*32), 16, 0, 0);
                __builtin_amdgcn_global_load_lds((cas1_void*)(Wlo + g), (as3_void*)(Wl + rb*32), 16, 0, 0);
            }
        } else {   // BN==64: waves 0-3 stage hi, waves 4-7 stage lo
            const int rb = (wid & 3) * 16;
            const size_t g = (size_t)(n0 + rb + rlo) * Kp + kk;
            const f16* src = (wid < 4) ? (Whi + g) : (Wlo + g);
            f16* dst = ((wid < 4) ? Wh : Wl) + rb*32;
            __builtin_amdgcn_global_load_lds((cas1_void*)src, (as3_void*)dst, 16, 0, 0);
        }
        if constexpr (!XCVT) {
            if constexpr (BM == 256) {
                #pragma unroll
                for (int c = 0; c < 2; ++c) {
                    const int rb = c * 128 + wid * 16;
                    const size_t g = (size_t)(m0 + rb + rlo) * Kp + kk;
                    __builtin_amdgcn_global_load_lds((cas1_void*)(Xhi + g), (as3_void*)(Xh + rb*32), 16, 0, 0);
                    __builtin_amdgcn_global_load_lds((cas1_void*)(Xlo + g), (as3_void*)(Xl + rb*32), 16, 0, 0);
                }
            } else {
                #pragma unroll
                for (int c = 0; c < 2; ++c) {
                    const int rb = wid * 32 + c * 16;
                    const size_t g = (size_t)(m0 + rb + rlo) * Kp + kk;
                    __builtin_amdgcn_global_load_lds((cas1_void*)(Xhi + g), (as3_void*)(Xh + rb*32), 16, 0, 0);
                    __builtin_amdgcn_global_load_lds((cas1_void*)(Xlo + g), (as3_void*)(Xl + rb*32), 16, 0, 0);
                }
            }
        } else {
            const int ar = tid >> 1;
            const int q0 = (tid & 1) * 2;
            const int fr = fswz(ar);
            const int k0 = kt * 32;
            const float* ap = X32 + (size_t)(m0 + ar) * ldx + (size_t)(k0 + q0 * 8);
            float v[16];
            if (k0 + 32 <= K_real) {
                float4 u0 = *(const float4*)(ap);
                float4 u1 = *(const float4*)(ap + 4);
                float4 u2 = *(const float4*)(ap + 8);
                float4 u3 = *(const float4*)(ap + 12);
                v[0]=u0.x; v[1]=u0.y; v[2]=u0.z; v[3]=u0.w;
                v[4]=u1.x; v[5]=u1.y; v[6]=u1.z; v[7]=u1.w;
                v[8]=u2.x; v[9]=u2.y; v[10]=u2.z; v[11]=u2.w;
                v[12]=u3.x; v[13]=u3.y; v[14]=u3.z; v[15]=u3.w;
            } else {
                #pragma unroll
                for (int j2 = 0; j2 < 16; ++j2) {
                    int kk2 = k0 + q0*8 + j2;
                    v[j2] = (kk2 < K_real) ? X32[(size_t)(m0 + ar) * ldx + kk2] : 0.f;
                }
            }
            #pragma unroll
            for (int h2 = 0; h2 < 2; ++h2) {
                f16x8 hv, lv;
                #pragma unroll
                for (int j2 = 0; j2 < 8; ++j2) {
                    float x = v[h2*8 + j2];
                    f16 hh = (f16)x;
                    hv[j2] = hh;
                    lv[j2] = (f16)(x - (float)hh);
                }
                const int dst = ar*32 + (((q0 + h2) ^ fr) << 3);
                *(f16x8*)&Xh[dst] = hv;
                *(f16x8*)&Xl[dst] = lv;
            }
        }
    };

    if constexpr (!XCVT) {
        // ---- DEEP path: counted-vmcnt pipeline, depth 2 (R1-proven) ----
        stage(0, 0);
        stage(1, 1);
        for (int t = 0; t < nk; ++t) {
            if (t + 1 < nk) {
                asm volatile("s_waitcnt vmcnt(%0)" :: "i"(GLL) : "memory");
            } else {
                asm volatile("s_waitcnt vmcnt(0)" ::: "memory");
            }
            __builtin_amdgcn_s_barrier();
            const f16* Xh = lds[t & 1];
            const f16* Xl = Xh + XSZ;
            const f16* Wh = Xl + XSZ;
            const f16* Wl = Wh + WSZ;
            f16x8 bh[NF], bl[NF], ah[MF], al[MF];
            #pragma unroll
            for (int j = 0; j < NF; ++j) {
                const int r = (wn + j*16 + lr) * 32 + koff;
                bh[j] = *(const f16x8*)&Wh[r];
                bl[j] = *(const f16x8*)&Wl[r];
            }
            #pragma unroll
            for (int i = 0; i < MF; ++i) {
                const int r = (wm + i*16 + lr) * 32 + koff;
                ah[i] = *(const f16x8*)&Xh[r];
                al[i] = *(const f16x8*)&Xl[r];
            }
            asm volatile("s_waitcnt lgkmcnt(0)" ::: "memory");
            __builtin_amdgcn_sched_barrier(0);
            __builtin_amdgcn_s_barrier();
            if (t + 2 < nk) stage(t & 1, t + 2);
            __builtin_amdgcn_s_setprio(1);
            #pragma unroll
            for (int i = 0; i < MF; ++i)
                #pragma unroll
                for (int j = 0; j < NF; ++j)
                    acc[i][j] = __builtin_amdgcn_mfma_f32_16x16x32_f16(ah[i], bh[j], acc[i][j], 0, 0, 0);
            #pragma unroll
            for (int i = 0; i < MF; ++i)
                #pragma unroll
                for (int j = 0; j < NF; ++j)
                    acc[i][j] = __builtin_amdgcn_mfma_f32_16x16x32_f16(ah[i], bl[j], acc[i][j], 0, 0, 0);
            #pragma unroll
            for (int i = 0; i < MF; ++i)
                #pragma unroll
                for (int j = 0; j < NF; ++j)
                    acc[i][j] = __builtin_amdgcn_mfma_f32_16x16x32_f16(al[i], bh[j], acc[i][j], 0, 0, 0);
            __builtin_amdgcn_s_setprio(0);
        }
    } else {
        // ---- XCVT path (enc1): old __syncthreads structure ----
        stage(0, 0);
        __syncthreads();
        for (int t = 0; t < nk; ++t) {
            if (t + 1 < nk) stage((t + 1) & 1, t + 1);
            const f16* Xh = lds[t & 1];
            const f16* Xl = Xh + XSZ;
            const f16* Wh = Xl + XSZ;
            const f16* Wl = Wh + WSZ;
            f16x8 bh[NF], bl[NF];
            #pragma unroll
            for (int j = 0; j < NF; ++j) {
                const int r = (wn + j*16 + lr) * 32 + koff;
                bh[j] = *(const f16x8*)&Wh[r];
                bl[j] = *(const f16x8*)&Wl[r];
            }
            __builtin_amdgcn_s_setprio(1);
            #pragma unroll
            for (int ih = 0; ih < MF; ih += 4) {
                f16x8 ah[4], al[4];
                #pragma unroll
                for (int i = 0; i < 4; ++i) {
                    const int r = (wm + (ih + i)*16 + lr) * 32 + koff;
                    ah[i] = *(const f16x8*)&Xh[r];
                    al[i] = *(const f16x8*)&Xl[r];
                }
                #pragma unroll
                for (int i = 0; i < 4; ++i)
                    #pragma unroll
                    for (int j = 0; j < NF; ++j)
                        acc[ih+i][j] = __builtin_amdgcn_mfma_f32_16x16x32_f16(ah[i], bh[j], acc[ih+i][j], 0, 0, 0);
                #pragma unroll
                for (int i = 0; i < 4; ++i)
                    #pragma unroll
                    for (int j = 0; j < NF; ++j)
                        acc[ih+i][j] = __builtin_amdgcn_mfma_f32_16x16x32_f16(ah[i], bl[j], acc[ih+i][j], 0, 0, 0);
                #pragma unroll
                for (int i = 0; i < 4; ++i)
                    #pragma unroll
                    for (int j = 0; j < NF; ++j)
                        acc[ih+i][j] = __builtin_amdgcn_mfma_f32_16x16x32_f16(al[i], bh[j], acc[ih+i][j], 0, 0, 0);
            }
            __builtin_amdgcn_s_setprio(0);
            __syncthreads();
        }
    }

    // epilogue
    #pragma unroll
    for (int i = 0; i < MF; ++i) {
        #pragma unroll
        for (int j = 0; j < NF; ++j) {
            const int col = n0 + wn + j*16 + lr;
            if (col >= N_real) continue;
            const float bcol = bias[col];
            #pragma unroll
            for (int q = 0; q < 4; ++q) {
                const int m = m0 + wm + i*16 + ls*4 + q;
                float vv = acc[i][j][q] + bcol;
                if (MODE == 0) {
                    C32[(size_t)m * N_real + col] = fmaxf(vv, 0.f);
                } else if (MODE == 1) {
                    vv = fmaxf(vv, 0.f);
                    f16 hi = (f16)vv;
                    const size_t idx = (size_t)m * NpOut + (size_t)(col ^ (fswz(m) << 3));
                    Chi[idx] = hi;
                    Clo[idx] = (f16)(vv - (float)hi);
                } else {
                    if (col >= halfN) vv = softplusf(vv) + 0.001f;
                    C32[(size_t)m * N_real + col] = vv;
                }
            }
        }
    }
}

// ---------------- gemm_dec3_areg: A-direct-to-reg, W-only LDS ----------------
// BM=128, BN=128, 256 thr = 4 waves (2m x 2n), per-wave 64x64 (MF=4, NF=4).
// A-fragments are wave-exclusive -> loaded straight from global (L2-served).
// W stays in LDS: dbuf hi/lo = 32 KB. Plain grid.
// R12: only change vs R11 is __launch_bounds__(256,4) -> 4 blocks/CU
// (LDS 4x32=128<=160 KB, VGPR 84<=128 at 4 waves/SIMD). Final occupancy probe
// within the A-reg structure; pre-committed: null => 414 is wave-serial floor.
// This schedule is otherwise the measured floor for dec3 (414 us, MfmaUtil
// 27.5): 4 alternative structures matched it; prefetch variants spilled;
// grid swizzles exploded cache traffic. Do not modify without full A/B.
__global__ __launch_bounds__(256, 4) void gemm_dec3_areg(
    const f16* __restrict__ Xhi, const f16* __restrict__ Xlo,
    const f16* __restrict__ Whi, const f16* __restrict__ Wlo,
    const float* __restrict__ bias, float* __restrict__ C32) {
    constexpr int WSZ = 128 * 32;               // f16 per half-buffer
    __shared__ f16 lds[2][2 * WSZ];             // 32 KB

    const int tid = threadIdx.x;
    const int wid = tid >> 6;
    const int lane = tid & 63;
    const int lr = lane & 15;
    const int ls = lane >> 4;
    const int m0 = blockIdx.y * 128;
    const int n0 = blockIdx.x * 128;
    const int wm = (wid >> 1) * 64;             // 2 m-wave-groups
    const int wn = (wid & 1) * 64;              // 2 n-wave-groups
    const int koff = ((ls ^ ((lr >> 1) & 3)) << 3);
    const int kk_s = (lane & 3) * 8;
    const int rlo = lane >> 2;

    // per-lane A row bases (pre-swizzled layout: addr = rowoff + t*32)
    const int f_a = (lr >> 1) & 3;              // fswz(row) for row = 16*i + lr
    size_t arow[4];
    #pragma unroll
    for (int i = 0; i < 4; ++i)
        arow[i] = (size_t)(m0 + wm + i*16 + lr) * NN0 + ((ls ^ f_a) << 3);

    f32x4 acc[4][4] = {};

    auto stageW = [&](int bi, int kt) {
        f16* Wh = lds[bi];
        f16* Wl = Wh + WSZ;
        const int kk = kt * 32 + kk_s;
        const int rb = wid * 32;
        #pragma unroll
        for (int c = 0; c < 2; ++c) {
            const size_t g = (size_t)(n0 + rb + c*16 + rlo) * NN0 + kk;
            __builtin_amdgcn_global_load_lds((cas1_void*)(Whi + g), (as3_void*)(Wh + (rb + c*16)*32), 16, 0, 0);
            __builtin_amdgcn_global_load_lds((cas1_void*)(Wlo + g), (as3_void*)(Wl + (rb + c*16)*32), 16, 0, 0);
        }
    };

    stageW(0, 0);
    __syncthreads();
    for (int t = 0; t < 16; ++t) {
        if (t + 1 < 16) stageW((t + 1) & 1, t + 1);
        // A: direct global -> reg (8 x dwordx4, wave-exclusive rows)
        f16x8 ah[4], al[4];
        #pragma unroll
        for (int i = 0; i < 4; ++i) {
            const size_t ga = arow[i] + (size_t)t * 32;
            ah[i] = *(const f16x8*)(Xhi + ga);
            al[i] = *(const f16x8*)(Xlo + ga);
        }
        // W: LDS frags
        const f16* Wh = lds[t & 1];
        const f16* Wl = Wh + WSZ;
        f16x8 bh[4], bl[4];
        #pragma unroll
        for (int j = 0; j < 4; ++j) {
            const int r = (wn + j*16 + lr) * 32 + koff;
            bh[j] = *(const f16x8*)&Wh[r];
            bl[j] = *(const f16x8*)&Wl[r];
        }
        __builtin_amdgcn_s_setprio(1);
        #pragma unroll
        for (int i = 0; i < 4; ++i)
            #pragma unroll
            for (int j = 0; j < 4; ++j)
                acc[i][j] = __builtin_amdgcn_mfma_f32_16x16x32_f16(ah[i], bh[j], acc[i][j], 0, 0, 0);
        #pragma unroll
        for (int i = 0; i < 4; ++i)
            #pragma unroll
            for (int j = 0; j < 4; ++j)
                acc[i][j] = __builtin_amdgcn_mfma_f32_16x16x32_f16(ah[i], bl[j], acc[i][j], 0, 0, 0);
        #pragma unroll
        for (int i = 0; i < 4; ++i)
            #pragma unroll
            for (int j = 0; j < 4; ++j)
                acc[i][j] = __builtin_amdgcn_mfma_f32_16x16x32_f16(al[i], bh[j], acc[i][j], 0, 0, 0);
        __builtin_amdgcn_s_setprio(0);
        __syncthreads();
    }

    // epilogue: col = lane&15, row = ls*4 + q; softplus on var half
    #pragma unroll
    for (int i = 0; i < 4; ++i) {
        #pragma unroll
        for (int j = 0; j < 4; ++j) {
            const int col = n0 + wn + j*16 + lr;
            if (col >= OUTF) continue;
            const float bcol = bias[col];
            #pragma unroll
            for (int q = 0; q < 4; ++q) {
                const int m = m0 + wm + i*16 + ls*4 + q;
                float vv = acc[i][j][q] + bcol;
                if (col >= IN_F) vv = softplusf(vv) + 0.001f;
                C32[(size_t)m * OUTF + col] = vv;
            }
        }
    }
}

extern "C" void kernel_launch(void* const* d_in, const int* in_sizes, int n_in,
                              void* d_out, int out_size, void* d_ws, size_t ws_size,
                              hipStream_t stream) {
    const float* input  = (const float*)d_in[0];
    const int*   treat  = (const int*)d_in[1];
    const float* enc_W1 = (const float*)d_in[2];
    const float* enc_b1 = (const float*)d_in[3];
    const float* enc_W2 = (const float*)d_in[4];
    const float* enc_b2 = (const float*)d_in[5];
    const float* T_W    = (const float*)d_in[6];
    const float* T_b    = (const float*)d_in[7];
    const float* dec_W1 = (const float*)d_in[8];
    const float* dec_b1 = (const float*)d_in[9];
    const float* dec_W2 = (const float*)d_in[10];
    const float* dec_b2 = (const float*)d_in[11];
    const float* dec_W3 = (const float*)d_in[12];
    const float* dec_b3 = (const float*)d_in[13];
    float* out = (float*)d_out;

    // ---- workspace layout ----
    uint8_t* p = (uint8_t*)d_ws;
    f16* h1hi = (f16*)p;  float* latA = (float*)p;  p += (size_t)BATCH*NN0*2;  // 8 MB
    f16* h1lo = (f16*)p;  float* latB = (float*)p;  p += (size_t)BATCH*NN0*2;  // 8 MB
    float* emb = (float*)p;  f16* h4hi = (f16*)p;   p += (size_t)BATCH*NN2*4;  // 8 MB
    f16* lathi = (f16*)p;  f16* h4lo = (f16*)p;     p += (size_t)BATCH*NN2*2;  // 4 MB
    f16* latlo = (f16*)p;                           p += (size_t)BATCH*NN2*2;  // 4 MB
    f16* w1hi = (f16*)p;               p += (size_t)NN0*KP1*2;
    f16* w1lo = (f16*)p;               p += (size_t)NN0*KP1*2;
    f16* w2hi = (f16*)p;               p += (size_t)NN2*NN0*2;
    f16* w2lo = (f16*)p;               p += (size_t)NN2*NN0*2;
    f16* dw1hi = (f16*)p;              p += (size_t)NN1*NN2*2;
    f16* dw1lo = (f16*)p;              p += (size_t)NN1*NN2*2;
    f16* dw2hi = (f16*)p;              p += (size_t)NN0*NN1*2;
    f16* dw2lo = (f16*)p;              p += (size_t)NN0*NN1*2;
    f16* dw3hi = (f16*)p;              p += (size_t)NP3*NN0*2;
    f16* dw3lo = (f16*)p;              p += (size_t)NP3*NN0*2;
    int* cnt   = (int*)p;              p += 32*4;
    int* pos   = (int*)p;              p += 32*4;
    int* epair = (int*)p;              p += (size_t)BATCH*2*4;
    int* rows  = (int*)p;              p += (size_t)NTREAT*BATCH*4;
    f16* h3hi = h1hi;
    f16* h3lo = h1lo;

    // ---- gating prep ----
    zero64_kernel<<<1, 64, 0, stream>>>(cnt);            // cnt[32] + pos[32]
    count_kernel<<<BATCH/256, 256, 0, stream>>>(treat, cnt);
    pair_kernel<<<BATCH/256, 256, 0, stream>>>(treat, cnt, epair);
    scatter_kernel<<<BATCH/256, 256, 0, stream>>>(epair, pos, rows);

    // ---- weight conversions (transpose + hi/lo split + swizzle + pad) ----
    convw_kernel<<<dim3((KP1+63)/64, NN0/64), 256, 0, stream>>>(enc_W1, w1hi, w1lo, IN_F, NN0, KP1);
    convw_kernel<<<dim3(NN0/64, NN2/64), 256, 0, stream>>>(enc_W2, w2hi, w2lo, NN0, NN2, NN0);
    convw_kernel<<<dim3(NN2/64, NN1/64), 256, 0, stream>>>(dec_W1, dw1hi, dw1lo, NN2, NN1, NN2);
    convw_kernel<<<dim3(NN1/64, NN0/64), 256, 0, stream>>>(dec_W2, dw2hi, dw2lo, NN1, NN0, NN1);
    convw_kernel<<<dim3(NN0/64, NP3/64), 256, 0, stream>>>(dec_W3, dw3hi, dw3lo, NN0, OUTF, NN0);

    // ---- network ----
    // enc1: [8192,5000(f32 direct)] @ w1^T, relu -> h1 (HL swizzled)
    gemm8<1, true, 64><<<dim3(NN0/64, BATCH/256), 512, 0, stream>>>(
        nullptr, nullptr, input, IN_F, w1hi, w1lo, enc_b1,
        nullptr, h1hi, h1lo, KP1, IN_F, NN0, NN0, 0);
    // enc2: [8192,512] @ w2^T, relu -> emb (f32)
    gemm8<0, false, 64><<<dim3(NN2/64, BATCH/256), 512, 0, stream>>>(
        h1hi, h1lo, nullptr, 0, w2hi, w2lo, enc_b2,
        emb, nullptr, nullptr, NN0, NN0, NN2, NN2, 0);
    // experts (grouped) — no memset: latconv gates unassigned slots via epair
    expert_gemm<<<dim3(NTREAT, BATCH/16), 256, 0, stream>>>(emb, T_W, T_b, pos, rows, latA, latB);
    latconv_kernel<<<BATCH*NN2/256, 256, 0, stream>>>(latA, latB, epair, lathi, latlo);
    // dec1: [8192,256] @ dw1^T, relu -> h3 (HL swizzled)
    gemm8<1, false, 64><<<dim3(NN1/64, BATCH/256), 512, 0, stream>>>(
        lathi, latlo, nullptr, 0, dw1hi, dw1lo, dec_b1,
        nullptr, h3hi, h3lo, NN2, NN2, NN1, NN1, 0);
    // dec2: [8192,512] @ dw2^T, relu -> h4 (HL swizzled)
    gemm8<1, false, 64><<<dim3(NN0/64, BATCH/256), 512, 0, stream>>>(
        h3hi, h3lo, nullptr, 0, dw2hi, dw2lo, dec_b2,
        nullptr, h4hi, h4lo, NN1, NN1, NN0, NN0, 0);
    // dec3: [8192,512] @ dw3^T + codex epilogue -> out
    // A-reg, W-only LDS (32 KB) -> 4 blk/CU (launch_bounds 256,4), plain grid
    gemm_dec3_areg<<<dim3(NP3/128, BATCH/128), 256, 0, stream>>>(
        h4hi, h4lo, dw3hi, dw3lo, dec_b3, out);
}

// Round 13
// 914.937 us; speedup vs baseline: 1.3294x; 1.3294x over previous
//
#include <hip/hip_runtime.h>
#include <hip/hip_bf16.h>
#include <hip/hip_fp16.h>
#include <math.h>

#define BATCH 8192
#define IN_F 5000
#define KP1 5024          // enc1 K padded to mult of 32
#define NN0 512
#define NN1 512
#define NN2 256
#define NTREAT 20
#define OUTF (2*IN_F)     // 10000
#define NP3 10240         // dec3 N padded to mult of 256

typedef _Float16 f16;
typedef _Float16 f16x8 __attribute__((ext_vector_type(8)));
typedef float f32x4 __attribute__((ext_vector_type(4)));
typedef __attribute__((address_space(3))) void as3_void;
typedef const __attribute__((address_space(1))) void cas1_void;

__device__ __forceinline__ int fswz(int row) { return (row >> 1) & 3; }

__device__ __forceinline__ float softplusf(float x) {
    return fmaxf(x, 0.f) + log1pf(expf(-fabsf(x)));
}

// ---------------- prep: gating ----------------
__global__ void zero64_kernel(int* __restrict__ p) {
    if (threadIdx.x < 64) p[threadIdx.x] = 0;
}
__global__ void count_kernel(const int* __restrict__ treat, int* __restrict__ cnt) {
    int b = blockIdx.x * blockDim.x + threadIdx.x;
    if (b >= BATCH) return;
    int t0 = treat[2*b], t1 = treat[2*b+1];
    if (t0 >= 1 && t0 <= NTREAT) atomicAdd(&cnt[t0], 1);
    if (t1 >= 1 && t1 <= NTREAT && t1 != t0) atomicAdd(&cnt[t1], 1);
}
__global__ void pair_kernel(const int* __restrict__ treat, const int* __restrict__ cnt,
                            int* __restrict__ epair) {
    int b = blockIdx.x * blockDim.x + threadIdx.x;
    if (b >= BATCH) return;
    int t0 = treat[2*b], t1 = treat[2*b+1];
    int e0 = (t0 >= 1 && t0 <= NTREAT && cnt[t0] > 1) ? (t0 - 1) : -1;
    int e1 = (t1 >= 1 && t1 <= NTREAT && t1 != t0 && cnt[t1] > 1) ? (t1 - 1) : -1;
    epair[2*b] = e0;
    epair[2*b+1] = e1;
}
__global__ void scatter_kernel(const int* __restrict__ epair, int* __restrict__ pos,
                               int* __restrict__ rows) {
    int b = blockIdx.x * blockDim.x + threadIdx.x;
    if (b >= BATCH) return;
    #pragma unroll
    for (int p = 0; p < 2; ++p) {
        int t = epair[2*b + p];
        if (t >= 0) {
            int x = atomicAdd(&pos[t], 1);
            rows[t * BATCH + x] = b * 2 + p;
        }
    }
}

// ---------------- weight convert: W[K][N] f32 -> Whi/Wlo [Np][Kp] f16 ----------------
// transposed, zero-padded, pre-swizzled: k-group q of row n at slot (q&3) ^ fswz(n)
__global__ __launch_bounds__(256) void convw_kernel(
    const float* __restrict__ W, f16* __restrict__ Whi, f16* __restrict__ Wlo,
    int K, int N, int Kp) {
    __shared__ float t[64][65];
    const int k0 = blockIdx.x * 64;
    const int n0 = blockIdx.y * 64;
    const int tid = threadIdx.x;
    #pragma unroll
    for (int i = 0; i < 16; ++i) {
        int idx = tid + i*256;
        int r = idx >> 6, c = idx & 63;
        float v = 0.f;
        if (k0 + r < K && n0 + c < N) v = W[(size_t)(k0+r)*N + n0 + c];
        t[r][c] = v;
    }
    __syncthreads();
    const int n = tid >> 2;
    const int q0 = (tid & 3) * 2;
    const int f = fswz(n0 + n);
    #pragma unroll
    for (int h = 0; h < 2; ++h) {
        int q = q0 + h;
        if (k0 + q*8 >= Kp) continue;
        f16x8 hv, lv;
        #pragma unroll
        for (int j = 0; j < 8; ++j) {
            float x = t[q*8 + j][n];
            f16 hi = (f16)x;
            hv[j] = hi;
            lv[j] = (f16)(x - (float)hi);
        }
        size_t base = (size_t)(n0 + n) * Kp + (size_t)(k0 + (((q & 3) ^ f) << 3) + (q >> 2) * 32);
        *(f16x8*)&Whi[base] = hv;
        *(f16x8*)&Wlo[base] = lv;
    }
}

// ---------------- grouped expert GEMM ----------------
// Writes only rows assigned to an expert; unassigned rows are never read
// downstream (latconv gates on epair), so no zero-init memset is needed.
__global__ __launch_bounds__(256) void expert_gemm(
    const float* __restrict__ emb, const float* __restrict__ T_W,
    const float* __restrict__ T_b, const int* __restrict__ pos,
    const int* __restrict__ rows, float* __restrict__ latA, float* __restrict__ latB) {
    const int t = blockIdx.x;
    const int n = pos[t];
    const int base = blockIdx.y * 16;
    if (base >= n) return;
    const int nr = min(16, n - base);
    __shared__ float se[16][256];
    __shared__ int ridx[16];
    const int tid = threadIdx.x;
    if (tid < 16) ridx[tid] = (tid < nr) ? rows[t * BATCH + base + tid] : 0;
    __syncthreads();
    #pragma unroll
    for (int s = 0; s < 16; ++s)
        se[s][tid] = (s < nr) ? emb[(size_t)(ridx[s] >> 1) * NN2 + tid] : 0.f;
    __syncthreads();
    float acc[16];
    const float bcol = T_b[t * NN2 + tid];
    #pragma unroll
    for (int s = 0; s < 16; ++s) acc[s] = bcol;
    const float* W = T_W + (size_t)t * NN2 * NN2 + tid;
    for (int d0 = 0; d0 < NN2; d0 += 4) {
        float w0 = W[(size_t)(d0+0) * NN2];
        float w1 = W[(size_t)(d0+1) * NN2];
        float w2 = W[(size_t)(d0+2) * NN2];
        float w3 = W[(size_t)(d0+3) * NN2];
        #pragma unroll
        for (int s = 0; s < 16; ++s) {
            float4 e = *(const float4*)&se[s][d0];
            acc[s] = fmaf(e.x, w0, fmaf(e.y, w1, fmaf(e.z, w2, fmaf(e.w, w3, acc[s]))));
        }
    }
    for (int s = 0; s < nr; ++s) {
        int rp = ridx[s];
        float* dst = (rp & 1) ? latB : latA;
        dst[(size_t)(rp >> 1) * NN2 + tid] = fmaxf(acc[s], 0.f);
    }
}

// latent = gated(latA) + gated(latB) -> hi/lo f16, pre-swizzled layout
// Gate on epair: slot p contributes only if epair[2m+p] >= 0 (expert assigned).
// Unassigned slots hold stale workspace data and must read as zero.
__global__ __launch_bounds__(256) void latconv_kernel(
    const float* __restrict__ latA, const float* __restrict__ latB,
    const int* __restrict__ epair,
    f16* __restrict__ lhi, f16* __restrict__ llo) {
    const int idx = blockIdx.x * 256 + threadIdx.x;
    const int m = idx >> 8, k = idx & 255;
    const float a = (epair[2*m]     >= 0) ? latA[idx] : 0.f;
    const float b = (epair[2*m + 1] >= 0) ? latB[idx] : 0.f;
    float v = a + b;
    f16 hi = (f16)v;
    size_t o = (size_t)m * NN2 + (size_t)(k ^ (fswz(m) << 3));
    lhi[o] = hi;
    llo[o] = (f16)(v - (float)hi);
}

// ---------------- gemm8: tiled MFMA GEMM, dbuf LDS, hi/lo f16 3-term ----------------
// (R1/R2-proven deep path; plain grid. Used for enc1/enc2/dec1/dec2.)
//   BM=256 BN= 64: 512 thr, waves 4m x 2n, per-wave  64x32, LDS  80 KB (2 blk/CU)
// DEEP path (non-XCVT): counted-vmcnt pipeline, prefetch depth 2.
// XCVT path (enc1): old __syncthreads structure (preconv tested R10: neutral,
// dropped — the 8x input re-read is L3-served and conversion overlaps MFMA).
// MODE 0: f32 relu. MODE 1: hi/lo f16 pre-swizzled relu (pitch NpOut).
template<int MODE, bool XCVT, int BN, int BM = 256>
__global__ __launch_bounds__((BM == 128) ? 256 : 512, 2) void gemm8(
    const f16* __restrict__ Xhi, const f16* __restrict__ Xlo,
    const float* __restrict__ X32, int ldx,
    const f16* __restrict__ Whi, const f16* __restrict__ Wlo,
    const float* __restrict__ bias,
    float* __restrict__ C32, f16* __restrict__ Chi, f16* __restrict__ Clo,
    int Kp, int K_real, int N_real, int NpOut, int halfN) {
    constexpr int NTH = (BM == 128) ? 256 : 512;
    constexpr int NWAVE = NTH / 64;
    constexpr int WN_WAVES = (BN == 256) ? 4 : 2;
    constexpr int WM_WAVES = NWAVE / WN_WAVES;
    constexpr int WMT = BM / WM_WAVES;
    constexpr int WNT = BN / WN_WAVES;
    constexpr int MF = WMT / 16;
    constexpr int NF = WNT / 16;
    constexpr int XSZ = BM * 32;
    constexpr int WSZ = BN * 32;
    constexpr int GLL = (BN == 64) ? 5 : 8;
    __shared__ f16 lds[2][2*XSZ + 2*WSZ];

    const int tid = threadIdx.x;
    const int wid = tid >> 6;
    const int lane = tid & 63;
    const int lr = lane & 15;
    const int ls = lane >> 4;
    const int m0 = blockIdx.y * BM;
    const int n0 = blockIdx.x * BN;
    const int wm = (wid / WN_WAVES) * WMT;
    const int wn = (wid % WN_WAVES) * WNT;
    const int koff = ((ls ^ ((lr >> 1) & 3)) << 3);
    const int nk = Kp / 32;

    f32x4 acc[MF][NF] = {};

    auto stage = [&](int bi, int kt) {
        f16* Xh = lds[bi];
        f16* Xl = Xh + XSZ;
        f16* Wh = Xl + XSZ;
        f16* Wl = Wh + WSZ;
        const int kk = kt * 32 + (lane & 3) * 8;
        const int rlo = lane >> 2;
        if constexpr (BN == 128) {
            #pragma unroll
            for (int c = 0; c < 2; ++c) {
                const int rb = wid * 32 + c * 16;
                const size_t g = (size_t)(n0 + rb + rlo) * Kp + kk;
                __builtin_amdgcn_global_load_lds((cas1_void*)(Whi + g), (as3_void*)(Wh + rb*32), 16, 0, 0);
                __builtin_amdgcn_global_load_lds((cas1_void*)(Wlo + g), (as3_void*)(Wl + rb*32), 16, 0, 0);
            }
        } else {   // BN==64: waves 0-3 stage hi, waves 4-7 stage lo
            const int rb = (wid & 3) * 16;
            const size_t g = (size_t)(n0 + rb + rlo) * Kp + kk;
            const f16* src = (wid < 4) ? (Whi + g) : (Wlo + g);
            f16* dst = ((wid < 4) ? Wh : Wl) + rb*32;
            __builtin_amdgcn_global_load_lds((cas1_void*)src, (as3_void*)dst, 16, 0, 0);
        }
        if constexpr (!XCVT) {
            if constexpr (BM == 256) {
                #pragma unroll
                for (int c = 0; c < 2; ++c) {
                    const int rb = c * 128 + wid * 16;
                    const size_t g = (size_t)(m0 + rb + rlo) * Kp + kk;
                    __builtin_amdgcn_global_load_lds((cas1_void*)(Xhi + g), (as3_void*)(Xh + rb*32), 16, 0, 0);
                    __builtin_amdgcn_global_load_lds((cas1_void*)(Xlo + g), (as3_void*)(Xl + rb*32), 16, 0, 0);
                }
            } else {
                #pragma unroll
                for (int c = 0; c < 2; ++c) {
                    const int rb = wid * 32 + c * 16;
                    const size_t g = (size_t)(m0 + rb + rlo) * Kp + kk;
                    __builtin_amdgcn_global_load_lds((cas1_void*)(Xhi + g), (as3_void*)(Xh + rb*32), 16, 0, 0);
                    __builtin_amdgcn_global_load_lds((cas1_void*)(Xlo + g), (as3_void*)(Xl + rb*32), 16, 0, 0);
                }
            }
        } else {
            const int ar = tid >> 1;
            const int q0 = (tid & 1) * 2;
            const int fr = fswz(ar);
            const int k0 = kt * 32;
            const float* ap = X32 + (size_t)(m0 + ar) * ldx + (size_t)(k0 + q0 * 8);
            float v[16];
            if (k0 + 32 <= K_real) {
                float4 u0 = *(const float4*)(ap);
                float4 u1 = *(const float4*)(ap + 4);
                float4 u2 = *(const float4*)(ap + 8);
                float4 u3 = *(const float4*)(ap + 12);
                v[0]=u0.x; v[1]=u0.y; v[2]=u0.z; v[3]=u0.w;
                v[4]=u1.x; v[5]=u1.y; v[6]=u1.z; v[7]=u1.w;
                v[8]=u2.x; v[9]=u2.y; v[10]=u2.z; v[11]=u2.w;
                v[12]=u3.x; v[13]=u3.y; v[14]=u3.z; v[15]=u3.w;
            } else {
                #pragma unroll
                for (int j2 = 0; j2 < 16; ++j2) {
                    int kk2 = k0 + q0*8 + j2;
                    v[j2] = (kk2 < K_real) ? X32[(size_t)(m0 + ar) * ldx + kk2] : 0.f;
                }
            }
            #pragma unroll
            for (int h2 = 0; h2 < 2; ++h2) {
                f16x8 hv, lv;
                #pragma unroll
                for (int j2 = 0; j2 < 8; ++j2) {
                    float x = v[h2*8 + j2];
                    f16 hh = (f16)x;
                    hv[j2] = hh;
                    lv[j2] = (f16)(x - (float)hh);
                }
                const int dst = ar*32 + (((q0 + h2) ^ fr) << 3);
                *(f16x8*)&Xh[dst] = hv;
                *(f16x8*)&Xl[dst] = lv;
            }
        }
    };

    if constexpr (!XCVT) {
        // ---- DEEP path: counted-vmcnt pipeline, depth 2 (R1-proven) ----
        stage(0, 0);
        stage(1, 1);
        for (int t = 0; t < nk; ++t) {
            if (t + 1 < nk) {
                asm volatile("s_waitcnt vmcnt(%0)" :: "i"(GLL) : "memory");
            } else {
                asm volatile("s_waitcnt vmcnt(0)" ::: "memory");
            }
            __builtin_amdgcn_s_barrier();
            const f16* Xh = lds[t & 1];
            const f16* Xl = Xh + XSZ;
            const f16* Wh = Xl + XSZ;
            const f16* Wl = Wh + WSZ;
            f16x8 bh[NF], bl[NF], ah[MF], al[MF];
            #pragma unroll
            for (int j = 0; j < NF; ++j) {
                const int r = (wn + j*16 + lr) * 32 + koff;
                bh[j] = *(const f16x8*)&Wh[r];
                bl[j] = *(const f16x8*)&Wl[r];
            }
            #pragma unroll
            for (int i = 0; i < MF; ++i) {
                const int r = (wm + i*16 + lr) * 32 + koff;
                ah[i] = *(const f16x8*)&Xh[r];
                al[i] = *(const f16x8*)&Xl[r];
            }
            asm volatile("s_waitcnt lgkmcnt(0)" ::: "memory");
            __builtin_amdgcn_sched_barrier(0);
            __builtin_amdgcn_s_barrier();
            if (t + 2 < nk) stage(t & 1, t + 2);
            __builtin_amdgcn_s_setprio(1);
            #pragma unroll
            for (int i = 0; i < MF; ++i)
                #pragma unroll
                for (int j = 0; j < NF; ++j)
                    acc[i][j] = __builtin_amdgcn_mfma_f32_16x16x32_f16(ah[i], bh[j], acc[i][j], 0, 0, 0);
            #pragma unroll
            for (int i = 0; i < MF; ++i)
                #pragma unroll
                for (int j = 0; j < NF; ++j)
                    acc[i][j] = __builtin_amdgcn_mfma_f32_16x16x32_f16(ah[i], bl[j], acc[i][j], 0, 0, 0);
            #pragma unroll
            for (int i = 0; i < MF; ++i)
                #pragma unroll
                for (int j = 0; j < NF; ++j)
                    acc[i][j] = __builtin_amdgcn_mfma_f32_16x16x32_f16(al[i], bh[j], acc[i][j], 0, 0, 0);
            __builtin_amdgcn_s_setprio(0);
        }
    } else {
        // ---- XCVT path (enc1): old __syncthreads structure ----
        stage(0, 0);
        __syncthreads();
        for (int t = 0; t < nk; ++t) {
            if (t + 1 < nk) stage((t + 1) & 1, t + 1);
            const f16* Xh = lds[t & 1];
            const f16* Xl = Xh + XSZ;
            const f16* Wh = Xl + XSZ;
            const f16* Wl = Wh + WSZ;
            f16x8 bh[NF], bl[NF];
            #pragma unroll
            for (int j = 0; j < NF; ++j) {
                const int r = (wn + j*16 + lr) * 32 + koff;
                bh[j] = *(const f16x8*)&Wh[r];
                bl[j] = *(const f16x8*)&Wl[r];
            }
            __builtin_amdgcn_s_setprio(1);
            #pragma unroll
            for (int ih = 0; ih < MF; ih += 4) {
                f16x8 ah[4], al[4];
                #pragma unroll
                for (int i = 0; i < 4; ++i) {
                    const int r = (wm + (ih + i)*16 + lr) * 32 + koff;
                    ah[i] = *(const f16x8*)&Xh[r];
                    al[i] = *(const f16x8*)&Xl[r];
                }
                #pragma unroll
                for (int i = 0; i < 4; ++i)
                    #pragma unroll
                    for (int j = 0; j < NF; ++j)
                        acc[ih+i][j] = __builtin_amdgcn_mfma_f32_16x16x32_f16(ah[i], bh[j], acc[ih+i][j], 0, 0, 0);
                #pragma unroll
                for (int i = 0; i < 4; ++i)
                    #pragma unroll
                    for (int j = 0; j < NF; ++j)
                        acc[ih+i][j] = __builtin_amdgcn_mfma_f32_16x16x32_f16(ah[i], bl[j], acc[ih+i][j], 0, 0, 0);
                #pragma unroll
                for (int i = 0; i < 4; ++i)
                    #pragma unroll
                    for (int j = 0; j < NF; ++j)
                        acc[ih+i][j] = __builtin_amdgcn_mfma_f32_16x16x32_f16(al[i], bh[j], acc[ih+i][j], 0, 0, 0);
            }
            __builtin_amdgcn_s_setprio(0);
            __syncthreads();
        }
    }

    // epilogue
    #pragma unroll
    for (int i = 0; i < MF; ++i) {
        #pragma unroll
        for (int j = 0; j < NF; ++j) {
            const int col = n0 + wn + j*16 + lr;
            if (col >= N_real) continue;
            const float bcol = bias[col];
            #pragma unroll
            for (int q = 0; q < 4; ++q) {
                const int m = m0 + wm + i*16 + ls*4 + q;
                float vv = acc[i][j][q] + bcol;
                if (MODE == 0) {
                    C32[(size_t)m * N_real + col] = fmaxf(vv, 0.f);
                } else if (MODE == 1) {
                    vv = fmaxf(vv, 0.f);
                    f16 hi = (f16)vv;
                    const size_t idx = (size_t)m * NpOut + (size_t)(col ^ (fswz(m) << 3));
                    Chi[idx] = hi;
                    Clo[idx] = (f16)(vv - (float)hi);
                } else {
                    if (col >= halfN) vv = softplusf(vv) + 0.001f;
                    C32[(size_t)m * N_real + col] = vv;
                }
            }
        }
    }
}

// ---------------- gemm_dec3_areg: A-direct-to-reg, W-only LDS (R11 exact) ----------------
// BM=128, BN=128, 256 thr = 4 waves (2m x 2n), per-wave 64x64 (MF=4, NF=4).
// A-fragments are wave-exclusive -> loaded straight from global (L2-served).
// W stays in LDS: dbuf hi/lo = 32 KB -> 3 blocks/CU. Plain grid.
// FINAL configuration. Measured floor for dec3 (414 us, MfmaUtil 27.5):
// - 4 alternative schedules (2-barrier 128/256-tile, 4-phase split, deep vmcnt)
//   all converge to 414 us;
// - A-prefetch in 3 forms (lambda arrays, unrolled arrays, named scalars) all
//   spill to scratch (VGPR pinned at 84 by the allocator);
// - launch_bounds(256,4) forces VGPR 84->64 and spills (R12: 689 us);
// - both XCD grid swizzles explode cache traffic (R3: +380 MB, R6: +1.5 GB).
// Do not modify without a full A/B against this exact source.
__global__ __launch_bounds__(256, 3) void gemm_dec3_areg(
    const f16* __restrict__ Xhi, const f16* __restrict__ Xlo,
    const f16* __restrict__ Whi, const f16* __restrict__ Wlo,
    const float* __restrict__ bias, float* __restrict__ C32) {
    constexpr int WSZ = 128 * 32;               // f16 per half-buffer
    __shared__ f16 lds[2][2 * WSZ];             // 32 KB

    const int tid = threadIdx.x;
    const int wid = tid >> 6;
    const int lane = tid & 63;
    const int lr = lane & 15;
    const int ls = lane >> 4;
    const int m0 = blockIdx.y * 128;
    const int n0 = blockIdx.x * 128;
    const int wm = (wid >> 1) * 64;             // 2 m-wave-groups
    const int wn = (wid & 1) * 64;              // 2 n-wave-groups
    const int koff = ((ls ^ ((lr >> 1) & 3)) << 3);
    const int kk_s = (lane & 3) * 8;
    const int rlo = lane >> 2;

    // per-lane A row bases (pre-swizzled layout: addr = rowoff + t*32)
    const int f_a = (lr >> 1) & 3;              // fswz(row) for row = 16*i + lr
    size_t arow[4];
    #pragma unroll
    for (int i = 0; i < 4; ++i)
        arow[i] = (size_t)(m0 + wm + i*16 + lr) * NN0 + ((ls ^ f_a) << 3);

    f32x4 acc[4][4] = {};

    auto stageW = [&](int bi, int kt) {
        f16* Wh = lds[bi];
        f16* Wl = Wh + WSZ;
        const int kk = kt * 32 + kk_s;
        const int rb = wid * 32;
        #pragma unroll
        for (int c = 0; c < 2; ++c) {
            const size_t g = (size_t)(n0 + rb + c*16 + rlo) * NN0 + kk;
            __builtin_amdgcn_global_load_lds((cas1_void*)(Whi + g), (as3_void*)(Wh + (rb + c*16)*32), 16, 0, 0);
            __builtin_amdgcn_global_load_lds((cas1_void*)(Wlo + g), (as3_void*)(Wl + (rb + c*16)*32), 16, 0, 0);
        }
    };

    stageW(0, 0);
    __syncthreads();
    for (int t = 0; t < 16; ++t) {
        if (t + 1 < 16) stageW((t + 1) & 1, t + 1);
        // A: direct global -> reg (8 x dwordx4, wave-exclusive rows)
        f16x8 ah[4], al[4];
        #pragma unroll
        for (int i = 0; i < 4; ++i) {
            const size_t ga = arow[i] + (size_t)t * 32;
            ah[i] = *(const f16x8*)(Xhi + ga);
            al[i] = *(const f16x8*)(Xlo + ga);
        }
        // W: LDS frags
        const f16* Wh = lds[t & 1];
        const f16* Wl = Wh + WSZ;
        f16x8 bh[4], bl[4];
        #pragma unroll
        for (int j = 0; j < 4; ++j) {
            const int r = (wn + j*16 + lr) * 32 + koff;
            bh[j] = *(const f16x8*)&Wh[r];
            bl[j] = *(const f16x8*)&Wl[r];
        }
        __builtin_amdgcn_s_setprio(1);
        #pragma unroll
        for (int i = 0; i < 4; ++i)
            #pragma unroll
            for (int j = 0; j < 4; ++j)
                acc[i][j] = __builtin_amdgcn_mfma_f32_16x16x32_f16(ah[i], bh[j], acc[i][j], 0, 0, 0);
        #pragma unroll
        for (int i = 0; i < 4; ++i)
            #pragma unroll
            for (int j = 0; j < 4; ++j)
                acc[i][j] = __builtin_amdgcn_mfma_f32_16x16x32_f16(ah[i], bl[j], acc[i][j], 0, 0, 0);
        #pragma unroll
        for (int i = 0; i < 4; ++i)
            #pragma unroll
            for (int j = 0; j < 4; ++j)
                acc[i][j] = __builtin_amdgcn_mfma_f32_16x16x32_f16(al[i], bh[j], acc[i][j], 0, 0, 0);
        __builtin_amdgcn_s_setprio(0);
        __syncthreads();
    }

    // epilogue: col = lane&15, row = ls*4 + q; softplus on var half
    #pragma unroll
    for (int i = 0; i < 4; ++i) {
        #pragma unroll
        for (int j = 0; j < 4; ++j) {
            const int col = n0 + wn + j*16 + lr;
            if (col >= OUTF) continue;
            const float bcol = bias[col];
            #pragma unroll
            for (int q = 0; q < 4; ++q) {
                const int m = m0 + wm + i*16 + ls*4 + q;
                float vv = acc[i][j][q] + bcol;
                if (col >= IN_F) vv = softplusf(vv) + 0.001f;
                C32[(size_t)m * OUTF + col] = vv;
            }
        }
    }
}

extern "C" void kernel_launch(void* const* d_in, const int* in_sizes, int n_in,
                              void* d_out, int out_size, void* d_ws, size_t ws_size,
                              hipStream_t stream) {
    const float* input  = (const float*)d_in[0];
    const int*   treat  = (const int*)d_in[1];
    const float* enc_W1 = (const float*)d_in[2];
    const float* enc_b1 = (const float*)d_in[3];
    const float* enc_W2 = (const float*)d_in[4];
    const float* enc_b2 = (const float*)d_in[5];
    const float* T_W    = (const float*)d_in[6];
    const float* T_b    = (const float*)d_in[7];
    const float* dec_W1 = (const float*)d_in[8];
    const float* dec_b1 = (const float*)d_in[9];
    const float* dec_W2 = (const float*)d_in[10];
    const float* dec_b2 = (const float*)d_in[11];
    const float* dec_W3 = (const float*)d_in[12];
    const float* dec_b3 = (const float*)d_in[13];
    float* out = (float*)d_out;

    // ---- workspace layout ----
    uint8_t* p = (uint8_t*)d_ws;
    f16* h1hi = (f16*)p;  float* latA = (float*)p;  p += (size_t)BATCH*NN0*2;  // 8 MB
    f16* h1lo = (f16*)p;  float* latB = (float*)p;  p += (size_t)BATCH*NN0*2;  // 8 MB
    float* emb = (float*)p;  f16* h4hi = (f16*)p;   p += (size_t)BATCH*NN2*4;  // 8 MB
    f16* lathi = (f16*)p;  f16* h4lo = (f16*)p;     p += (size_t)BATCH*NN2*2;  // 4 MB
    f16* latlo = (f16*)p;                           p += (size_t)BATCH*NN2*2;  // 4 MB
    f16* w1hi = (f16*)p;               p += (size_t)NN0*KP1*2;
    f16* w1lo = (f16*)p;               p += (size_t)NN0*KP1*2;
    f16* w2hi = (f16*)p;               p += (size_t)NN2*NN0*2;
    f16* w2lo = (f16*)p;               p += (size_t)NN2*NN0*2;
    f16* dw1hi = (f16*)p;              p += (size_t)NN1*NN2*2;
    f16* dw1lo = (f16*)p;              p += (size_t)NN1*NN2*2;
    f16* dw2hi = (f16*)p;              p += (size_t)NN0*NN1*2;
    f16* dw2lo = (f16*)p;              p += (size_t)NN0*NN1*2;
    f16* dw3hi = (f16*)p;              p += (size_t)NP3*NN0*2;
    f16* dw3lo = (f16*)p;              p += (size_t)NP3*NN0*2;
    int* cnt   = (int*)p;              p += 32*4;
    int* pos   = (int*)p;              p += 32*4;
    int* epair = (int*)p;              p += (size_t)BATCH*2*4;
    int* rows  = (int*)p;              p += (size_t)NTREAT*BATCH*4;
    f16* h3hi = h1hi;
    f16* h3lo = h1lo;

    // ---- gating prep ----
    zero64_kernel<<<1, 64, 0, stream>>>(cnt);            // cnt[32] + pos[32]
    count_kernel<<<BATCH/256, 256, 0, stream>>>(treat, cnt);
    pair_kernel<<<BATCH/256, 256, 0, stream>>>(treat, cnt, epair);
    scatter_kernel<<<BATCH/256, 256, 0, stream>>>(epair, pos, rows);

    // ---- weight conversions (transpose + hi/lo split + swizzle + pad) ----
    convw_kernel<<<dim3((KP1+63)/64, NN0/64), 256, 0, stream>>>(enc_W1, w1hi, w1lo, IN_F, NN0, KP1);
    convw_kernel<<<dim3(NN0/64, NN2/64), 256, 0, stream>>>(enc_W2, w2hi, w2lo, NN0, NN2, NN0);
    convw_kernel<<<dim3(NN2/64, NN1/64), 256, 0, stream>>>(dec_W1, dw1hi, dw1lo, NN2, NN1, NN2);
    convw_kernel<<<dim3(NN1/64, NN0/64), 256, 0, stream>>>(dec_W2, dw2hi, dw2lo, NN1, NN0, NN1);
    convw_kernel<<<dim3(NN0/64, NP3/64), 256, 0, stream>>>(dec_W3, dw3hi, dw3lo, NN0, OUTF, NN0);

    // ---- network ----
    // enc1: [8192,5000(f32 direct)] @ w1^T, relu -> h1 (HL swizzled)
    gemm8<1, true, 64><<<dim3(NN0/64, BATCH/256), 512, 0, stream>>>(
        nullptr, nullptr, input, IN_F, w1hi, w1lo, enc_b1,
        nullptr, h1hi, h1lo, KP1, IN_F, NN0, NN0, 0);
    // enc2: [8192,512] @ w2^T, relu -> emb (f32)
    gemm8<0, false, 64><<<dim3(NN2/64, BATCH/256), 512, 0, stream>>>(
        h1hi, h1lo, nullptr, 0, w2hi, w2lo, enc_b2,
        emb, nullptr, nullptr, NN0, NN0, NN2, NN2, 0);
    // experts (grouped) — no memset: latconv gates unassigned slots via epair
    expert_gemm<<<dim3(NTREAT, BATCH/16), 256, 0, stream>>>(emb, T_W, T_b, pos, rows, latA, latB);
    latconv_kernel<<<BATCH*NN2/256, 256, 0, stream>>>(latA, latB, epair, lathi, latlo);
    // dec1: [8192,256] @ dw1^T, relu -> h3 (HL swizzled)
    gemm8<1, false, 64><<<dim3(NN1/64, BATCH/256), 512, 0, stream>>>(
        lathi, latlo, nullptr, 0, dw1hi, dw1lo, dec_b1,
        nullptr, h3hi, h3lo, NN2, NN2, NN1, NN1, 0);
    // dec2: [8192,512] @ dw2^T, relu -> h4 (HL swizzled)
    gemm8<1, false, 64><<<dim3(NN0/64, BATCH/256), 512, 0, stream>>>(
        h3hi, h3lo, nullptr, 0, dw2hi, dw2lo, dec_b2,
        nullptr, h4hi, h4lo, NN1, NN1, NN0, NN0, 0);
    // dec3: [8192,512] @ dw3^T + codex epilogue -> out
    // R11-exact: A-reg, W-only LDS (32 KB) -> 3 blk/CU, plain grid
    gemm_dec3_areg<<<dim3(NP3/128, BATCH/128), 256, 0, stream>>>(
        h4hi, h4lo, dw3hi, dw3lo, dec_b3, out);
}